// Round 7
// baseline (291.383 us; speedup 1.0000x reference)
//
#include <hip/hip_runtime.h>
#include <stdint.h>

#define Mdim 8192
#define Ndim 4096
#define Kdim 4096

#define BM 256
#define BN 256
#define BK 32
#define NT (Kdim / BK)   // 128 K-tiles

typedef float f32x4 __attribute__((ext_vector_type(4)));
typedef __bf16 bf16x8 __attribute__((ext_vector_type(8)));
typedef unsigned short ushort_t;

#define FMAXC 3.3858093490333422e+38f  // FLT_MAX * (1 - 0.005)

__device__ __forceinline__ ushort_t f2bf(float f) {
    unsigned u = __float_as_uint(f);
    u += 0x7fffu + ((u >> 16) & 1u);   // round-to-nearest-even
    return (ushort_t)(u >> 16);
}

__device__ __forceinline__ void gload_lds16(const void* g, void* l) {
    __builtin_amdgcn_global_load_lds(
        (const __attribute__((address_space(1))) uint32_t*)g,
        (__attribute__((address_space(3))) uint32_t*)(uint32_t)(uintptr_t)l,
        16, 0, 0);
}

// ---------------------------------------------------------------------------
// Kernel 1: dequant + CSR outliers -> bf16 weight row. Unchanged (passed).
// ---------------------------------------------------------------------------
__global__ __launch_bounds__(128) void dequant_kernel(
        const int* __restrict__ qw, const float* __restrict__ lut,
        const int* __restrict__ rows, const int* __restrict__ cols,
        const float* __restrict__ vals, ushort_t* __restrict__ w16) {
    __shared__ float wrow[128 * 33];
    __shared__ float slut[16];
    const int o = blockIdx.x;
    const int t = threadIdx.x;

    if (t < 16) slut[t] = lut[o * 16 + t];
    __syncthreads();

    const int q0 = qw[0 * Ndim * 128 + o * 128 + t];
    const int q1 = qw[1 * Ndim * 128 + o * 128 + t];
    const int q2 = qw[2 * Ndim * 128 + o * 128 + t];
    const int q3 = qw[3 * Ndim * 128 + o * 128 + t];
    float* dst = &wrow[t * 33];
#pragma unroll
    for (int j = 0; j < 32; ++j) {
        int idx = (((q0 >> j) & 1) << 3) | (((q1 >> j) & 1) << 2) |
                  (((q2 >> j) & 1) << 1) | ((q3 >> j) & 1);
        dst[j] = slut[idx];
    }
    __syncthreads();

    const int beg = rows[o], end = rows[o + 1];
    for (int k = beg + t; k < end; k += 128) {
        int c = cols[k];
        atomicAdd(&wrow[c + (c >> 5)], vals[k]);
    }
    __syncthreads();

    __align__(16) ushort_t tmp[32];
#pragma unroll
    for (int j = 0; j < 32; ++j) tmp[j] = f2bf(dst[j]);
    uint4* dstg = (uint4*)(w16 + (size_t)o * Kdim + t * 32);
    const uint4* srcg = (const uint4*)tmp;
#pragma unroll
    for (int j = 0; j < 4; ++j) dstg[j] = srcg[j];
}

// ---------------------------------------------------------------------------
// Kernel 2: x f32 -> bf16. Unchanged (HBM-bound, ~30 us).
// ---------------------------------------------------------------------------
__global__ __launch_bounds__(256) void convx_kernel(
        const float* __restrict__ x, ushort_t* __restrict__ y) {
    size_t i = ((size_t)blockIdx.x * 256 + threadIdx.x) * 8;
    float4 a = *(const float4*)(x + i);
    float4 b = *(const float4*)(x + i + 4);
    __align__(16) ushort_t r[8] = {f2bf(a.x), f2bf(a.y), f2bf(a.z), f2bf(a.w),
                                   f2bf(b.x), f2bf(b.y), f2bf(b.z), f2bf(b.w)};
    *(uint4*)(y + i) = *(const uint4*)r;
}

// ---------------------------------------------------------------------------
// Kernel 3: bf16 GEMM, 256x256 tile, BK=32, 4-buffer LDS ring, 2-phase
// double-barrier schedule with WAITCNT HYGIENE per the m201/m218 template:
//   - __builtin_amdgcn_s_barrier() (no implied vmcnt/lgkm drain), NOT
//     asm "s_barrier" with "memory" clobber (that forces a full drain in
//     the waitcnt pass and silently turns counted-vmcnt into drain-0).
//   - clobber-free asm "s_waitcnt vmcnt(N)" pinned with sched_barrier(0).
//   - lgkmcnt left to the compiler (register-dependency tracked).
//   - branchless main loop (tail peeled) so no conditional staging.
// Geometry/swizzle/ring identical to round 3 (passed): 8 waves (2M x 4N),
// wave tile 128x64, acc[8][4]; A ring 4x16KB @0, B ring 4x16KB @65536;
// zero-conflict paired-row swizzle; stage distance 2, vmcnt(4) per tile.
// RAW: vmcnt(4) at end of tile t -> only tile-(t+2)'s 4 loads outstanding,
//      so tile t+1 is LDS-resident before any wave reads it next iter.
// WAR: stage(t+2) writes buf (t-2)&3, whose reads retired before the
//      end-of-(t-2) barrier, >=2 barriers before this stage issues.
// ---------------------------------------------------------------------------
__global__ __launch_bounds__(512, 2) void gemm_kernel(
        const ushort_t* __restrict__ A, const ushort_t* __restrict__ Bw,
        const float* __restrict__ bias, float* __restrict__ C) {
    __shared__ __align__(16) char lds[131072];

    // XCD swizzle, bn-fastest: 32 concurrent blocks per XCD share one A panel
    // (L2-resident), stream B via L3. nwg=512 (%8==0).
    const int wgid = blockIdx.x;
    const int swz = (wgid & 7) * 64 + (wgid >> 3);
    const int bn = swz & 15, bm = swz >> 4;
    const int m0 = bm * BM, n0 = bn * BN;

    const int tid = threadIdx.x;
    const int lane = tid & 63, wid = tid >> 6;
    const int wr = wid >> 2, wc = wid & 3;       // 2M x 4N wave grid
    const int fr = lane & 15, kg = lane >> 4;

    // ---- staging geometry (inverse-swizzled global source, linear LDS dest)
    const int sline = tid >> 3;
    const int slot = (tid & 7) ^ (sline & 7);
    const int srow0 = (sline << 1) + (slot >> 2);          // + j*128
    const int skel = (slot & 3) * 8;                       // k elements
    const ushort_t* gA = A + (size_t)(m0 + srow0) * Kdim + skel;
    const ushort_t* gB = Bw + (size_t)(n0 + srow0) * Kdim + skel;

    // ---- ds_read lane offset (row = base + fr, kslot = kg)
    const int offL = (fr >> 1) * 128 + (((((fr & 1) << 2) | kg) ^ (fr >> 1)) << 4);

    f32x4 acc[8][4];
#pragma unroll
    for (int i = 0; i < 8; ++i)
#pragma unroll
        for (int j = 0; j < 4; ++j) acc[i][j] = (f32x4){0.f, 0.f, 0.f, 0.f};

    // running stage pointers: at iteration t they point at K-tile t+2
    const ushort_t* pA = gA;
    const ushort_t* pB = gB;

    auto stageA = [&](int bufd) {
        char* d = lds + bufd * 16384 + tid * 16;
        gload_lds16(pA, d);
        gload_lds16(pA + (size_t)128 * Kdim, d + 8192);
    };
    auto stageB = [&](int bufd) {
        char* d = lds + 65536 + bufd * 16384 + tid * 16;
        gload_lds16(pB, d);
        gload_lds16(pB + (size_t)128 * Kdim, d + 8192);
    };

    // ---- prologue: stage tiles 0,1 -> bufs 0,1; tile 0+1... wait tile 0,1
    stageA(0); stageB(0); pA += BK; pB += BK;
    stageA(1); stageB(1); pA += BK; pB += BK;
    asm volatile("s_waitcnt vmcnt(4)");        // tile 0 resident
    __builtin_amdgcn_sched_barrier(0);
    __builtin_amdgcn_s_barrier();

#pragma unroll 1
    for (int t = 0; t < NT - 2; ++t) {
        const int bufi = t & 3;
        const int buf2 = (t + 2) & 3;
        const char* Ab = lds + bufi * 16384;
        const char* Bb = lds + 65536 + bufi * 16384;

        // ===== phase 0: read A[m0-3] + B[all n]; stage A(t+2) =====
        bf16x8 Af0[4], Bf[4];
#pragma unroll
        for (int m = 0; m < 4; ++m)
            Af0[m] = *(const bf16x8*)(Ab + wr * 8192 + m * 1024 + offL);
#pragma unroll
        for (int n = 0; n < 4; ++n)
            Bf[n] = *(const bf16x8*)(Bb + wc * 4096 + n * 1024 + offL);
        stageA(buf2);
        __builtin_amdgcn_s_barrier();
        __builtin_amdgcn_s_setprio(1);
#pragma unroll
        for (int m = 0; m < 4; ++m)
#pragma unroll
            for (int n = 0; n < 4; ++n)
                acc[m][n] = __builtin_amdgcn_mfma_f32_16x16x32_bf16(
                    Af0[m], Bf[n], acc[m][n], 0, 0, 0);
        __builtin_amdgcn_s_setprio(0);
        __builtin_amdgcn_s_barrier();

        // ===== phase 1: read A[m4-7]; stage B(t+2) =====
        bf16x8 Af1[4];
#pragma unroll
        for (int m = 0; m < 4; ++m)
            Af1[m] = *(const bf16x8*)(Ab + wr * 8192 + (m + 4) * 1024 + offL);
        stageB(buf2);
        pA += BK; pB += BK;
        __builtin_amdgcn_s_barrier();
        __builtin_amdgcn_s_setprio(1);
#pragma unroll
        for (int m = 0; m < 4; ++m)
#pragma unroll
            for (int n = 0; n < 4; ++n)
                acc[m + 4][n] = __builtin_amdgcn_mfma_f32_16x16x32_bf16(
                    Af1[m], Bf[n], acc[m + 4][n], 0, 0, 0);
        __builtin_amdgcn_s_setprio(0);
        asm volatile("s_waitcnt vmcnt(4)");    // tile t+1 resident
        __builtin_amdgcn_sched_barrier(0);
        __builtin_amdgcn_s_barrier();
    }

    // ===== tail: tiles NT-2 and NT-1 (no staging) =====
#pragma unroll 1
    for (int t = NT - 2; t < NT; ++t) {
        const int bufi = t & 3;
        const char* Ab = lds + bufi * 16384;
        const char* Bb = lds + 65536 + bufi * 16384;

        bf16x8 Af0[4], Bf[4];
#pragma unroll
        for (int m = 0; m < 4; ++m)
            Af0[m] = *(const bf16x8*)(Ab + wr * 8192 + m * 1024 + offL);
#pragma unroll
        for (int n = 0; n < 4; ++n)
            Bf[n] = *(const bf16x8*)(Bb + wc * 4096 + n * 1024 + offL);
        __builtin_amdgcn_s_barrier();
        __builtin_amdgcn_s_setprio(1);
#pragma unroll
        for (int m = 0; m < 4; ++m)
#pragma unroll
            for (int n = 0; n < 4; ++n)
                acc[m][n] = __builtin_amdgcn_mfma_f32_16x16x32_bf16(
                    Af0[m], Bf[n], acc[m][n], 0, 0, 0);
        __builtin_amdgcn_s_setprio(0);
        __builtin_amdgcn_s_barrier();

        bf16x8 Af1[4];
#pragma unroll
        for (int m = 0; m < 4; ++m)
            Af1[m] = *(const bf16x8*)(Ab + wr * 8192 + (m + 4) * 1024 + offL);
        __builtin_amdgcn_s_barrier();
        __builtin_amdgcn_s_setprio(1);
#pragma unroll
        for (int m = 0; m < 4; ++m)
#pragma unroll
            for (int n = 0; n < 4; ++n)
                acc[m + 4][n] = __builtin_amdgcn_mfma_f32_16x16x32_bf16(
                    Af1[m], Bf[n], acc[m + 4][n], 0, 0, 0);
        __builtin_amdgcn_s_setprio(0);
        asm volatile("s_waitcnt vmcnt(0)");    // drain remaining staged loads
        __builtin_amdgcn_sched_barrier(0);
        __builtin_amdgcn_s_barrier();
    }

    // ---- epilogue: C/D layout col = lane&15, row = (lane>>4)*4 + reg
    const int rg = lane >> 4;
#pragma unroll
    for (int nf = 0; nf < 4; ++nf) {
        const int col = n0 + wc * 64 + nf * 16 + fr;
        const float bv = bias[col];
#pragma unroll
        for (int mf = 0; mf < 8; ++mf) {
            const int row = m0 + wr * 128 + mf * 16 + rg * 4;
            float* outp = C + (size_t)row * Ndim + col;
#pragma unroll
            for (int j = 0; j < 4; ++j) {
                float v = acc[mf][nf][j] + bv;
                v = fminf(fmaxf(v, -FMAXC), FMAXC);
                outp[(size_t)j * Ndim] = v;
            }
        }
    }
}

extern "C" void kernel_launch(void* const* d_in, const int* in_sizes, int n_in,
                              void* d_out, int out_size, void* d_ws, size_t ws_size,
                              hipStream_t stream) {
    const float* x    = (const float*)d_in[0];
    const int*   qw   = (const int*)d_in[1];
    const float* lut  = (const float*)d_in[2];
    const int*   rows = (const int*)d_in[3];
    const int*   cols = (const int*)d_in[4];
    const float* vals = (const float*)d_in[5];
    const float* bias = (const float*)d_in[6];
    float* out = (float*)d_out;

    ushort_t* x16 = (ushort_t*)d_ws;                       // 64 MiB
    ushort_t* w16 = x16 + (size_t)Mdim * Kdim;             // 32 MiB

    hipLaunchKernelGGL(dequant_kernel, dim3(Ndim), dim3(128), 0, stream,
                       qw, lut, rows, cols, vals, w16);
    hipLaunchKernelGGL(convx_kernel, dim3((Mdim * Kdim) / (256 * 8)), dim3(256), 0, stream,
                       x, x16);
    hipLaunchKernelGGL(gemm_kernel, dim3((Mdim / BM) * (Ndim / BN)), dim3(512), 0, stream,
                       x16, w16, bias, out);
}

// Round 8
// 282.149 us; speedup vs baseline: 1.0327x; 1.0327x over previous
//
#include <hip/hip_runtime.h>
#include <stdint.h>

#define Mdim 8192
#define Ndim 4096
#define Kdim 4096

#define BM 256
#define BN 256
#define BK 32
#define NT (Kdim / BK)   // 128 K-tiles

typedef float f32x4 __attribute__((ext_vector_type(4)));
typedef __bf16 bf16x8 __attribute__((ext_vector_type(8)));
typedef unsigned short ushort_t;

#define FMAXC 3.3858093490333422e+38f  // FLT_MAX * (1 - 0.005)

__device__ __forceinline__ ushort_t f2bf(float f) {
    unsigned u = __float_as_uint(f);
    u += 0x7fffu + ((u >> 16) & 1u);   // round-to-nearest-even
    return (ushort_t)(u >> 16);
}

__device__ __forceinline__ void gload_lds16(const void* g, void* l) {
    __builtin_amdgcn_global_load_lds(
        (const __attribute__((address_space(1))) uint32_t*)g,
        (__attribute__((address_space(3))) uint32_t*)(uint32_t)(uintptr_t)l,
        16, 0, 0);
}

#define SGB(mask, n) __builtin_amdgcn_sched_group_barrier(mask, n, 0)

// ---------------------------------------------------------------------------
// Kernel 1: dequant + CSR outliers -> bf16 weight row. Unchanged (passed).
// ---------------------------------------------------------------------------
__global__ __launch_bounds__(128) void dequant_kernel(
        const int* __restrict__ qw, const float* __restrict__ lut,
        const int* __restrict__ rows, const int* __restrict__ cols,
        const float* __restrict__ vals, ushort_t* __restrict__ w16) {
    __shared__ float wrow[128 * 33];
    __shared__ float slut[16];
    const int o = blockIdx.x;
    const int t = threadIdx.x;

    if (t < 16) slut[t] = lut[o * 16 + t];
    __syncthreads();

    const int q0 = qw[0 * Ndim * 128 + o * 128 + t];
    const int q1 = qw[1 * Ndim * 128 + o * 128 + t];
    const int q2 = qw[2 * Ndim * 128 + o * 128 + t];
    const int q3 = qw[3 * Ndim * 128 + o * 128 + t];
    float* dst = &wrow[t * 33];
#pragma unroll
    for (int j = 0; j < 32; ++j) {
        int idx = (((q0 >> j) & 1) << 3) | (((q1 >> j) & 1) << 2) |
                  (((q2 >> j) & 1) << 1) | ((q3 >> j) & 1);
        dst[j] = slut[idx];
    }
    __syncthreads();

    const int beg = rows[o], end = rows[o + 1];
    for (int k = beg + t; k < end; k += 128) {
        int c = cols[k];
        atomicAdd(&wrow[c + (c >> 5)], vals[k]);
    }
    __syncthreads();

    __align__(16) ushort_t tmp[32];
#pragma unroll
    for (int j = 0; j < 32; ++j) tmp[j] = f2bf(dst[j]);
    uint4* dstg = (uint4*)(w16 + (size_t)o * Kdim + t * 32);
    const uint4* srcg = (const uint4*)tmp;
#pragma unroll
    for (int j = 0; j < 4; ++j) dstg[j] = srcg[j];
}

// ---------------------------------------------------------------------------
// Kernel 2: x f32 -> bf16. Unchanged (HBM-bound, ~30 us).
// ---------------------------------------------------------------------------
__global__ __launch_bounds__(256) void convx_kernel(
        const float* __restrict__ x, ushort_t* __restrict__ y) {
    size_t i = ((size_t)blockIdx.x * 256 + threadIdx.x) * 8;
    float4 a = *(const float4*)(x + i);
    float4 b = *(const float4*)(x + i + 4);
    __align__(16) ushort_t r[8] = {f2bf(a.x), f2bf(a.y), f2bf(a.z), f2bf(a.w),
                                   f2bf(b.x), f2bf(b.y), f2bf(b.z), f2bf(b.w)};
    *(uint4*)(y + i) = *(const uint4*)r;
}

// ---------------------------------------------------------------------------
// Kernel 3: bf16 GEMM, 256x256, BK=32, ring-4 LDS, register frag dbuf,
// BRANCHLESS main loop (tail peeled) so each half-tile is ONE scheduling
// region, + sched_group_barrier interleave {VMEM,MFMA}x2 {DS_READ,2 MFMA}x12
// {MFMA x4} -> ds_read/stage issue fills MFMA pipe windows (DS unit and
// matrix pipe overlap instead of alternating).
// Pipeline: iter-half processes tile u: MFMA(u) from frags read last half;
// reads frags(u+1); stages tile u+3; vmcnt(4) -> u+1 resident; s_barrier.
// RAW: per-wave vmcnt(4) leaves only tile-(u+3) loads outstanding; barrier
//      globalizes -> frags(u+1) safe to read next half.
// WAR: stage(u+3) overwrites buf[(u-1)&3]; its reads completed before the
//      lgkm wait ahead of MFMA(u-1), >=2 barriers before this stage issues.
// ---------------------------------------------------------------------------
__global__ __launch_bounds__(512, 2) void gemm_kernel(
        const ushort_t* __restrict__ A, const ushort_t* __restrict__ Bw,
        const float* __restrict__ bias, float* __restrict__ C) {
    __shared__ __align__(16) char lds[131072];

    // XCD swizzle, bn-fastest: 32 concurrent blocks per XCD share one A panel
    // (L2-resident), stream B via L3. nwg=512 (%8==0).
    const int wgid = blockIdx.x;
    const int swz = (wgid & 7) * 64 + (wgid >> 3);
    const int bn = swz & 15, bm = swz >> 4;
    const int m0 = bm * BM, n0 = bn * BN;

    const int tid = threadIdx.x;
    const int lane = tid & 63, wid = tid >> 6;
    const int wr = wid >> 2, wc = wid & 3;       // 2M x 4N wave grid
    const int fr = lane & 15, kg = lane >> 4;

    // ---- staging geometry (inverse-swizzled global source, linear LDS dest)
    const int sline = tid >> 3;
    const int slot = (tid & 7) ^ (sline & 7);
    const int srow0 = (sline << 1) + (slot >> 2);          // + j*128
    const int skel = (slot & 3) * 8;                       // k elements
    const ushort_t* gA = A + (size_t)(m0 + srow0) * Kdim + skel;
    const ushort_t* gB = Bw + (size_t)(n0 + srow0) * Kdim + skel;

    // ---- ds_read lane offset (row = base + fr, kslot = kg)
    const int offL = (fr >> 1) * 128 + (((((fr & 1) << 2) | kg) ^ (fr >> 1)) << 4);

    f32x4 acc[8][4];
#pragma unroll
    for (int i = 0; i < 8; ++i)
#pragma unroll
        for (int j = 0; j < 4; ++j) acc[i][j] = (f32x4){0.f, 0.f, 0.f, 0.f};

    // running stage pointers (advance BK per tile staged)
    const ushort_t* pA = gA;
    const ushort_t* pB = gB;

    auto stageA = [&](int bufd) {
        char* d = lds + bufd * 16384 + tid * 16;
        gload_lds16(pA, d);
        gload_lds16(pA + (size_t)128 * Kdim, d + 8192);
    };
    auto stageB = [&](int bufd) {
        char* d = lds + 65536 + bufd * 16384 + tid * 16;
        gload_lds16(pB, d);
        gload_lds16(pB + (size_t)128 * Kdim, d + 8192);
    };
    auto readFrags = [&](bf16x8 (&FA)[8], bf16x8 (&FB)[4], int bufidx) {
        const char* Ab = lds + bufidx * 16384;
        const char* Bb = lds + 65536 + bufidx * 16384;
#pragma unroll
        for (int n = 0; n < 4; ++n) {
            FA[n] = *(const bf16x8*)(Ab + wr * 8192 + n * 1024 + offL);
            FB[n] = *(const bf16x8*)(Bb + wc * 4096 + n * 1024 + offL);
        }
#pragma unroll
        for (int m = 4; m < 8; ++m)
            FA[m] = *(const bf16x8*)(Ab + wr * 8192 + m * 1024 + offL);
    };
    auto mfmaTile = [&](bf16x8 (&FA)[8], bf16x8 (&FB)[4]) {
#pragma unroll
        for (int m = 0; m < 8; ++m)
#pragma unroll
            for (int n = 0; n < 4; ++n)
                acc[m][n] = __builtin_amdgcn_mfma_f32_16x16x32_bf16(
                    FA[m], FB[n], acc[m][n], 0, 0, 0);
    };
    // interleave layout for one half-tile: 4 VMEM + 12 DS_READ + 32 MFMA
    auto sgbHalf = [&]() {
        SGB(0x30, 2); SGB(0x8, 2);
        SGB(0x30, 2); SGB(0x8, 2);
#pragma unroll
        for (int i = 0; i < 12; ++i) { SGB(0x100, 1); SGB(0x8, 2); }
        SGB(0x8, 4);
    };

    // ---- prologue: stage tiles 0,1,2 -> bufs 0,1,2
    stageA(0); stageB(0); pA += BK; pB += BK;
    stageA(1); stageB(1); pA += BK; pB += BK;
    stageA(2); stageB(2); pA += BK; pB += BK;
    asm volatile("s_waitcnt vmcnt(4)");        // tiles 0,1 resident
    __builtin_amdgcn_sched_barrier(0);
    __builtin_amdgcn_s_barrier();

    bf16x8 FAa[8], FAb[8];
    bf16x8 FBa[4], FBb[4];
    readFrags(FAa, FBa, 0);                    // tile 0 -> set a

    // ===== main loop: tiles 0..123, fully branchless halves =====
#pragma unroll 1
    for (int t = 0; t < NT - 4; t += 2) {
        // --- half 1: MFMA tile t (a); read t+1 -> b; stage t+3 ---
        readFrags(FAb, FBb, (t + 1) & 3);
        stageA((t + 3) & 3); stageB((t + 3) & 3);
        pA += BK; pB += BK;
        mfmaTile(FAa, FBa);
        sgbHalf();
        asm volatile("s_waitcnt vmcnt(4)");    // tile t+1 resident
        __builtin_amdgcn_sched_barrier(0);
        __builtin_amdgcn_s_barrier();

        // --- half 2: MFMA tile t+1 (b); read t+2 -> a; stage t+4 ---
        readFrags(FAa, FBa, (t + 2) & 3);
        stageA((t + 4) & 3); stageB((t + 4) & 3);
        pA += BK; pB += BK;
        mfmaTile(FAb, FBb);
        sgbHalf();
        asm volatile("s_waitcnt vmcnt(4)");    // tile t+2 resident
        __builtin_amdgcn_sched_barrier(0);
        __builtin_amdgcn_s_barrier();
    }

    // ===== peel A: tiles 124,125 (stage 127 only) =====
    {
        readFrags(FAb, FBb, 125 & 3);
        stageA(127 & 3); stageB(127 & 3);
        mfmaTile(FAa, FBa);
        sgbHalf();
        asm volatile("s_waitcnt vmcnt(4)");    // tile 126 resident
        __builtin_amdgcn_sched_barrier(0);
        __builtin_amdgcn_s_barrier();

        readFrags(FAa, FBa, 126 & 3);
        mfmaTile(FAb, FBb);
        asm volatile("s_waitcnt vmcnt(0)");    // tile 127 resident
        __builtin_amdgcn_sched_barrier(0);
        __builtin_amdgcn_s_barrier();
    }

    // ===== peel B: tiles 126,127 (no staging, no barriers needed) =====
    {
        readFrags(FAb, FBb, 127 & 3);
        mfmaTile(FAa, FBa);
        mfmaTile(FAb, FBb);
    }

    // ---- epilogue: C/D layout col = lane&15, row = (lane>>4)*4 + reg
    const int rg = lane >> 4;
#pragma unroll
    for (int nf = 0; nf < 4; ++nf) {
        const int col = n0 + wc * 64 + nf * 16 + fr;
        const float bv = bias[col];
#pragma unroll
        for (int mf = 0; mf < 8; ++mf) {
            const int row = m0 + wr * 128 + mf * 16 + rg * 4;
            float* outp = C + (size_t)row * Ndim + col;
#pragma unroll
            for (int j = 0; j < 4; ++j) {
                float v = acc[mf][nf][j] + bv;
                v = fminf(fmaxf(v, -FMAXC), FMAXC);
                outp[(size_t)j * Ndim] = v;
            }
        }
    }
}

extern "C" void kernel_launch(void* const* d_in, const int* in_sizes, int n_in,
                              void* d_out, int out_size, void* d_ws, size_t ws_size,
                              hipStream_t stream) {
    const float* x    = (const float*)d_in[0];
    const int*   qw   = (const int*)d_in[1];
    const float* lut  = (const float*)d_in[2];
    const int*   rows = (const int*)d_in[3];
    const int*   cols = (const int*)d_in[4];
    const float* vals = (const float*)d_in[5];
    const float* bias = (const float*)d_in[6];
    float* out = (float*)d_out;

    ushort_t* x16 = (ushort_t*)d_ws;                       // 64 MiB
    ushort_t* w16 = x16 + (size_t)Mdim * Kdim;             // 32 MiB

    hipLaunchKernelGGL(dequant_kernel, dim3(Ndim), dim3(128), 0, stream,
                       qw, lut, rows, cols, vals, w16);
    hipLaunchKernelGGL(convx_kernel, dim3((Mdim * Kdim) / (256 * 8)), dim3(256), 0, stream,
                       x, x16);
    hipLaunchKernelGGL(gemm_kernel, dim3((Mdim / BM) * (Ndim / BN)), dim3(512), 0, stream,
                       x16, w16, bias, out);
}

// Round 9
// 275.700 us; speedup vs baseline: 1.0569x; 1.0234x over previous
//
#include <hip/hip_runtime.h>
#include <stdint.h>

#define Mdim 8192
#define Ndim 4096
#define Kdim 4096

#define BM 256
#define BN 256
#define BK 64
#define NT2 (Kdim / BK)   // 64 K-tiles

typedef float f32x4 __attribute__((ext_vector_type(4)));
typedef __bf16 bf16x8 __attribute__((ext_vector_type(8)));
typedef unsigned short ushort_t;

#define FMAXC 3.3858093490333422e+38f  // FLT_MAX * (1 - 0.005)

__device__ __forceinline__ ushort_t f2bf(float f) {
    unsigned u = __float_as_uint(f);
    u += 0x7fffu + ((u >> 16) & 1u);   // round-to-nearest-even
    return (ushort_t)(u >> 16);
}

__device__ __forceinline__ void gload_lds16(const void* g, void* l) {
    __builtin_amdgcn_global_load_lds(
        (const __attribute__((address_space(1))) uint32_t*)g,
        (__attribute__((address_space(3))) uint32_t*)(uint32_t)(uintptr_t)l,
        16, 0, 0);
}

#define SGB(mask, n) __builtin_amdgcn_sched_group_barrier(mask, n, 0)

// ---------------------------------------------------------------------------
// Kernel 1: dequant + CSR outliers -> bf16 weight row. Unchanged (passed).
// ---------------------------------------------------------------------------
__global__ __launch_bounds__(128) void dequant_kernel(
        const int* __restrict__ qw, const float* __restrict__ lut,
        const int* __restrict__ rows, const int* __restrict__ cols,
        const float* __restrict__ vals, ushort_t* __restrict__ w16) {
    __shared__ float wrow[128 * 33];
    __shared__ float slut[16];
    const int o = blockIdx.x;
    const int t = threadIdx.x;

    if (t < 16) slut[t] = lut[o * 16 + t];
    __syncthreads();

    const int q0 = qw[0 * Ndim * 128 + o * 128 + t];
    const int q1 = qw[1 * Ndim * 128 + o * 128 + t];
    const int q2 = qw[2 * Ndim * 128 + o * 128 + t];
    const int q3 = qw[3 * Ndim * 128 + o * 128 + t];
    float* dst = &wrow[t * 33];
#pragma unroll
    for (int j = 0; j < 32; ++j) {
        int idx = (((q0 >> j) & 1) << 3) | (((q1 >> j) & 1) << 2) |
                  (((q2 >> j) & 1) << 1) | ((q3 >> j) & 1);
        dst[j] = slut[idx];
    }
    __syncthreads();

    const int beg = rows[o], end = rows[o + 1];
    for (int k = beg + t; k < end; k += 128) {
        int c = cols[k];
        atomicAdd(&wrow[c + (c >> 5)], vals[k]);
    }
    __syncthreads();

    __align__(16) ushort_t tmp[32];
#pragma unroll
    for (int j = 0; j < 32; ++j) tmp[j] = f2bf(dst[j]);
    uint4* dstg = (uint4*)(w16 + (size_t)o * Kdim + t * 32);
    const uint4* srcg = (const uint4*)tmp;
#pragma unroll
    for (int j = 0; j < 4; ++j) dstg[j] = srcg[j];
}

// ---------------------------------------------------------------------------
// Kernel 2: x f32 -> bf16. Unchanged (HBM-bound, ~30 us).
// ---------------------------------------------------------------------------
__global__ __launch_bounds__(256) void convx_kernel(
        const float* __restrict__ x, ushort_t* __restrict__ y) {
    size_t i = ((size_t)blockIdx.x * 256 + threadIdx.x) * 8;
    float4 a = *(const float4*)(x + i);
    float4 b = *(const float4*)(x + i + 4);
    __align__(16) ushort_t r[8] = {f2bf(a.x), f2bf(a.y), f2bf(a.z), f2bf(a.w),
                                   f2bf(b.x), f2bf(b.y), f2bf(b.z), f2bf(b.w)};
    *(uint4*)(y + i) = *(const uint4*)r;
}

// ---------------------------------------------------------------------------
// Kernel 3: bf16 GEMM, 256x256 tile, BK=64, classic LDS double-buffer,
// ONE barrier per K-tile, 64 MFMA/wave between barriers (2x amortization
// of per-tile fixed overhead vs BK=32).
//   8 waves (2M x 4N), wave tile 128x64, acc[8][4].
//   LDS 128 KiB: buf d at d*65536: A[256][64] @+0, B[256][64] @+32768.
//   Swizzle (128-B rows, 8 slots of 16B): slot' = slot ^ (row&7);
//   realized as linear gload_lds dest + inverse-swizzled global source +
//   swizzled ds_read. 8 lanes/slot = minimum bank occupancy (conflict-free).
// Schedule per tile (branchless; SGB pins emission):
//   {12 ds_read k0} {2 stage-VMEM,4 MFMA}x4 {2 ds_read k1,2 MFMA}x6 {36 MFMA}
//   then vmcnt(0) (stages issued ~2500cyc earlier -> free), s_barrier.
// Correctness (textbook dbuf): stage(t+1) writes buf (t+1)&1; tile t-1's
// reads of that buf were consumed by MFMAs before the end-of-(t-1) barrier.
// vmcnt(0)+barrier at end of t -> tile t+1 resident before anyone reads it.
// ---------------------------------------------------------------------------
__global__ __launch_bounds__(512, 2) void gemm_kernel(
        const ushort_t* __restrict__ A, const ushort_t* __restrict__ Bw,
        const float* __restrict__ bias, float* __restrict__ C) {
    __shared__ __align__(16) char lds[131072];

    // XCD swizzle, bn-fastest: 32 concurrent blocks per XCD share one A panel
    // (L2-resident), stream B via L3. nwg=512 (%8==0).
    const int wgid = blockIdx.x;
    const int swz = (wgid & 7) * 64 + (wgid >> 3);
    const int bn = swz & 15, bm = swz >> 4;
    const int m0 = bm * BM, n0 = bn * BN;

    const int tid = threadIdx.x;
    const int lane = tid & 63, wid = tid >> 6;
    const int wr = wid >> 2, wc = wid & 3;       // 2M x 4N wave grid
    const int fr = lane & 15, kg = lane >> 4;

    // ---- staging geometry: thread tid writes LDS offsets tid*16 + j*8192
    //   (row = tid>>3 + j*64, slotpos = tid&7). Source slot = slotpos^(row&7).
    const int srow = tid >> 3;
    const int scol = (((tid & 7) ^ (srow & 7)) * 8);       // k elements
    const ushort_t* gA = A + (size_t)(m0 + srow) * Kdim + scol;
    const ushort_t* gB = Bw + (size_t)(n0 + srow) * Kdim + scol;

    // ---- ds_read swizzled offsets per k-step (row byte-stride 128)
    const int off0 = fr * 128 + (((kg) ^ (fr & 7)) << 4);
    const int off1 = fr * 128 + (((4 | kg) ^ (fr & 7)) << 4);

    f32x4 acc[8][4];
#pragma unroll
    for (int i = 0; i < 8; ++i)
#pragma unroll
        for (int j = 0; j < 4; ++j) acc[i][j] = (f32x4){0.f, 0.f, 0.f, 0.f};

    auto stage = [&](int buf, int t1) {
        const ushort_t* sa = gA + (size_t)t1 * BK;
        const ushort_t* sb = gB + (size_t)t1 * BK;
        char* da = lds + buf * 65536 + tid * 16;
        char* db = da + 32768;
#pragma unroll
        for (int j = 0; j < 4; ++j) {
            gload_lds16(sa + (size_t)j * 64 * Kdim, da + j * 8192);
            gload_lds16(sb + (size_t)j * 64 * Kdim, db + j * 8192);
        }
    };
    auto readA = [&](bf16x8 (&FA)[8], const char* Ab, int off) {
#pragma unroll
        for (int m = 0; m < 8; ++m)
            FA[m] = *(const bf16x8*)(Ab + wr * 16384 + m * 2048 + off);
    };
    auto readB = [&](bf16x8 (&FB)[4], const char* Bb, int off) {
#pragma unroll
        for (int n = 0; n < 4; ++n)
            FB[n] = *(const bf16x8*)(Bb + wc * 8192 + n * 2048 + off);
    };
    auto mfmaK = [&](bf16x8 (&FA)[8], bf16x8 (&FB)[4]) {
#pragma unroll
        for (int m = 0; m < 8; ++m)
#pragma unroll
            for (int n = 0; n < 4; ++n)
                acc[m][n] = __builtin_amdgcn_mfma_f32_16x16x32_bf16(
                    FA[m], FB[n], acc[m][n], 0, 0, 0);
    };

    // ---- prologue: stage tile 0 -> buf 0
    stage(0, 0);
    asm volatile("s_waitcnt vmcnt(0)");
    __builtin_amdgcn_sched_barrier(0);
    __builtin_amdgcn_s_barrier();

    // ===== main loop: tiles 0..NT2-2, one barrier per tile =====
#pragma unroll 1
    for (int t = 0; t < NT2 - 1; ++t) {
        const char* Ab = lds + (t & 1) * 65536;
        const char* Bb = Ab + 32768;

        bf16x8 A0[8], B0[4], A1[8], B1[4];
        readA(A0, Ab, off0); readB(B0, Bb, off0);
        stage((t + 1) & 1, t + 1);
        readA(A1, Ab, off1); readB(B1, Bb, off1);

        __builtin_amdgcn_s_setprio(1);
        mfmaK(A0, B0);
        mfmaK(A1, B1);
        __builtin_amdgcn_s_setprio(0);

        // SGB emission layout: 12 DS(k0) | {2 VMEM,4 MFMA}x4 | {2 DS,2 MFMA}x6 | 36 MFMA
        SGB(0x100, 12);
#pragma unroll
        for (int i = 0; i < 4; ++i) { SGB(0x30, 2); SGB(0x8, 4); }
#pragma unroll
        for (int i = 0; i < 6; ++i) { SGB(0x100, 2); SGB(0x8, 2); }
        SGB(0x8, 36);

        asm volatile("s_waitcnt vmcnt(0)");    // stages issued ~full tile ago
        __builtin_amdgcn_sched_barrier(0);
        __builtin_amdgcn_s_barrier();
    }

    // ===== tail: tile NT2-1 (no staging, no barrier) =====
    {
        const char* Ab = lds + ((NT2 - 1) & 1) * 65536;
        const char* Bb = Ab + 32768;
        bf16x8 A0[8], B0[4], A1[8], B1[4];
        readA(A0, Ab, off0); readB(B0, Bb, off0);
        readA(A1, Ab, off1); readB(B1, Bb, off1);
        mfmaK(A0, B0);
        mfmaK(A1, B1);
    }

    // ---- epilogue: C/D layout col = lane&15, row = (lane>>4)*4 + reg
    const int rg = lane >> 4;
#pragma unroll
    for (int nf = 0; nf < 4; ++nf) {
        const int col = n0 + wc * 64 + nf * 16 + fr;
        const float bv = bias[col];
#pragma unroll
        for (int mf = 0; mf < 8; ++mf) {
            const int row = m0 + wr * 128 + mf * 16 + rg * 4;
            float* outp = C + (size_t)row * Ndim + col;
#pragma unroll
            for (int j = 0; j < 4; ++j) {
                float v = acc[mf][nf][j] + bv;
                v = fminf(fmaxf(v, -FMAXC), FMAXC);
                outp[(size_t)j * Ndim] = v;
            }
        }
    }
}

extern "C" void kernel_launch(void* const* d_in, const int* in_sizes, int n_in,
                              void* d_out, int out_size, void* d_ws, size_t ws_size,
                              hipStream_t stream) {
    const float* x    = (const float*)d_in[0];
    const int*   qw   = (const int*)d_in[1];
    const float* lut  = (const float*)d_in[2];
    const int*   rows = (const int*)d_in[3];
    const int*   cols = (const int*)d_in[4];
    const float* vals = (const float*)d_in[5];
    const float* bias = (const float*)d_in[6];
    float* out = (float*)d_out;

    ushort_t* x16 = (ushort_t*)d_ws;                       // 64 MiB
    ushort_t* w16 = x16 + (size_t)Mdim * Kdim;             // 32 MiB

    hipLaunchKernelGGL(dequant_kernel, dim3(Ndim), dim3(128), 0, stream,
                       qw, lut, rows, cols, vals, w16);
    hipLaunchKernelGGL(convx_kernel, dim3((Mdim * Kdim) / (256 * 8)), dim3(256), 0, stream,
                       x, x16);
    hipLaunchKernelGGL(gemm_kernel, dim3((Mdim / BM) * (Ndim / BN)), dim3(512), 0, stream,
                       x16, w16, bias, out);
}